// Round 5
// baseline (436.311 us; speedup 1.0000x reference)
//
#include <hip/hip_runtime.h>
#include <cstdint>
#include <math.h>

typedef unsigned short u16;
typedef __bf16 bf16x8 __attribute__((ext_vector_type(8)));
typedef float f32x4 __attribute__((ext_vector_type(4)));

constexpr int Bc = 2, Sc = 2048, Dc = 1024, Hc = 16, DHc = 64;

__device__ __forceinline__ u16 f2bf(float f) {
  uint32_t u = __builtin_bit_cast(uint32_t, f);
  u += 0x7fffu + ((u >> 16) & 1u);
  return (u16)(u >> 16);
}
__device__ __forceinline__ float bf2f(u16 h) {
  uint32_t u = ((uint32_t)h) << 16;
  return __builtin_bit_cast(float, u);
}
__device__ __forceinline__ f32x4 mfma16(bf16x8 a, bf16x8 b, f32x4 c) {
  return __builtin_amdgcn_mfma_f32_16x16x32_bf16(a, b, c, 0, 0, 0);
}
__device__ __forceinline__ uint4 pack8(const float4& a, const float4& b) {
  uint4 o;
  o.x = (uint32_t)f2bf(a.x) | ((uint32_t)f2bf(a.y) << 16);
  o.y = (uint32_t)f2bf(a.z) | ((uint32_t)f2bf(a.w) << 16);
  o.z = (uint32_t)f2bf(b.x) | ((uint32_t)f2bf(b.y) << 16);
  o.w = (uint32_t)f2bf(b.z) | ((uint32_t)f2bf(b.w) << 16);
  return o;
}

// ---------------- bf16 GEMM, A may be f32 (converted during staging), B is f32.
// C[m][n] = (sum_k A[m][k]*B[n][k] + bias[n]) * scale
template <bool AF32>
__global__ __launch_bounds__(256) void gemm_bt(
    const void* __restrict__ Av, const float* __restrict__ Bw,
    const float* __restrict__ bias, int M, int N, int K, float scale,
    u16* __restrict__ outb, float* __restrict__ outf,
    int DHn, long strideB, long strideS, long strideH, long strideE) {
  constexpr int LDK = 40;  // 32 + 8 pad -> conflict-free ds_read_b128
  __shared__ u16 As[128 * LDK];
  __shared__ u16 Bs[128 * LDK];
  const int tid = threadIdx.x;
  const int lane = tid & 63;
  const int w = tid >> 6, wm = w >> 1, wn = w & 1;
  const int lo = lane & 15, hi = lane >> 4;
  const int m0 = blockIdx.y * 128, n0 = blockIdx.x * 128;
  const f32x4 vzero = {0.f, 0.f, 0.f, 0.f};

  f32x4 acc[4][4];
  #pragma unroll
  for (int i = 0; i < 4; ++i)
    #pragma unroll
    for (int j = 0; j < 4; ++j) acc[i][j] = vzero;

  for (int k0 = 0; k0 < K; k0 += 32) {
    #pragma unroll
    for (int it = 0; it < 2; ++it) {
      const int e = (tid + it * 256) * 8;
      const int r = e >> 5, c = e & 31;
      if (AF32) {
        const float* Af = (const float*)Av;
        const float4 u0 = *reinterpret_cast<const float4*>(&Af[(long)(m0 + r) * K + k0 + c]);
        const float4 u1 = *reinterpret_cast<const float4*>(&Af[(long)(m0 + r) * K + k0 + c + 4]);
        *reinterpret_cast<uint4*>(&As[r * LDK + c]) = pack8(u0, u1);
      } else {
        const u16* Ab = (const u16*)Av;
        *reinterpret_cast<uint4*>(&As[r * LDK + c]) =
            *reinterpret_cast<const uint4*>(&Ab[(long)(m0 + r) * K + k0 + c]);
      }
      int nr = n0 + r; nr = nr < N ? nr : N - 1;  // clamp (vproj N=64)
      const float4 w0 = *reinterpret_cast<const float4*>(&Bw[(long)nr * K + k0 + c]);
      const float4 w1 = *reinterpret_cast<const float4*>(&Bw[(long)nr * K + k0 + c + 4]);
      *reinterpret_cast<uint4*>(&Bs[r * LDK + c]) = pack8(w0, w1);
    }
    __syncthreads();
    bf16x8 af[4], bfr[4];
    #pragma unroll
    for (int mi = 0; mi < 4; ++mi)
      af[mi] = *reinterpret_cast<const bf16x8*>(&As[(wm * 64 + mi * 16 + lo) * LDK + hi * 8]);
    #pragma unroll
    for (int nj = 0; nj < 4; ++nj)
      bfr[nj] = *reinterpret_cast<const bf16x8*>(&Bs[(wn * 64 + nj * 16 + lo) * LDK + hi * 8]);
    #pragma unroll
    for (int mi = 0; mi < 4; ++mi)
      #pragma unroll
      for (int nj = 0; nj < 4; ++nj)
        acc[mi][nj] = mfma16(af[mi], bfr[nj], acc[mi][nj]);
    __syncthreads();
  }

  #pragma unroll
  for (int nj = 0; nj < 4; ++nj) {
    const int n = n0 + wn * 64 + nj * 16 + lo;
    if (n >= N) continue;
    const float bb = bias ? bias[n] : 0.f;
    const int hh = n / DHn, ee = n % DHn;
    #pragma unroll
    for (int mi = 0; mi < 4; ++mi) {
      #pragma unroll
      for (int r = 0; r < 4; ++r) {
        const int mm = m0 + wm * 64 + mi * 16 + hi * 4 + r;
        const int bidx = mm >> 11, ss = mm & 2047;  // S = 2048
        const long idx = bidx * strideB + ss * strideS + hh * strideH + ee * strideE;
        const float val = (acc[mi][nj][r] + bb) * scale;
        if (outf) outf[idx] = val;
        else outb[idx] = f2bf(val);
      }
    }
  }
}

// ---------------- flash stats+PV: single sweep, online softmax with wave-uniform scale.
// Swapped-operand: lane (lo,hi) owns q-row s0+lo; t = t0+c*16+hi*4+r.
// qh pre-scaled by log2(e)/8 (exp2 domain). Outputs off = m + log2(l) and outh.
__global__ __launch_bounds__(256, 2) void attn_stats(
    const u16* __restrict__ qh, const u16* __restrict__ kh,
    const u16* __restrict__ vT, u16* __restrict__ outh,
    float* __restrict__ off) {
  __shared__ u16 plds[4 * 16 * 80];  // per-wave transpose buffer
  const int tid = threadIdx.x;
  const int lane = tid & 63, w = tid >> 6;
  const int lo = lane & 15, hi = lane >> 4;
  const int blk = blockIdx.x;
  const int jj = blk & 15, bhz = blk >> 4;  // 16 pair-groups x 32 (b,h)
  const int b = bhz >> 4;
  const long bh = (long)bhz * Sc;
  u16* pbuf = &plds[w * 16 * 80];
  const f32x4 vzero = {0.f, 0.f, 0.f, 0.f};
  const int pr = jj * 4 + w;  // pair id 0..63 -> strips {pr, 127-pr}: equal work/wave

  #pragma unroll 1
  for (int sp = 0; sp < 2; ++sp) {
    const int strip = sp ? 127 - pr : pr;
    const int s0 = strip * 16;
    const int srow = s0 + lo;
    const int send = (s0 + 79) & ~63;  // live region end, 64-aligned

    bf16x8 qa0, qa1;
    {
      const u16* qp = &qh[(bh + s0 + lo) * DHc];
      qa0 = *reinterpret_cast<const bf16x8*>(&qp[hi * 8]);
      qa1 = *reinterpret_cast<const bf16x8*>(&qp[32 + hi * 8]);
    }

    float hatm = -1e30f, l = 0.f;
    f32x4 acco[4];
    #pragma unroll
    for (int eb = 0; eb < 4; ++eb) acco[eb] = vzero;

    bf16x8 kbA[8], vbA[8], kbB[8], vbB[8];

    auto PREF = [&](bf16x8 (&kb)[8], bf16x8 (&vb)[8], int t0) {
      #pragma unroll
      for (int c = 0; c < 4; ++c) {
        const u16* kp = &kh[(bh + t0 + c * 16 + lo) * DHc];
        kb[2 * c]     = *reinterpret_cast<const bf16x8*>(&kp[hi * 8]);
        kb[2 * c + 1] = *reinterpret_cast<const bf16x8*>(&kp[32 + hi * 8]);
      }
      #pragma unroll
      for (int eb = 0; eb < 4; ++eb) {
        const u16* vp = &vT[((long)b * DHc + eb * 16 + lo) * Sc + t0 + hi * 8];
        vb[2 * eb]     = *reinterpret_cast<const bf16x8*>(&vp[0]);
        vb[2 * eb + 1] = *reinterpret_cast<const bf16x8*>(&vp[32]);
      }
    };

    auto STEP = [&](bf16x8 (&kb)[8], bf16x8 (&vb)[8],
                    bf16x8 (&kbn)[8], bf16x8 (&vbn)[8], int t0) {
      if (t0 >= send) return;            // wave-uniform guard
      if (t0 + 64 < send) PREF(kbn, vbn, t0 + 64);
      f32x4 z[4];
      #pragma unroll
      for (int c = 0; c < 4; ++c)
        z[c] = mfma16(kb[2 * c + 1], qa1, mfma16(kb[2 * c], qa0, vzero));
      const bool maskstep = (t0 + 63 > s0);  // only the final step crosses the diagonal
      if (maskstep) {
        #pragma unroll
        for (int c = 0; c < 4; ++c)
          #pragma unroll
          for (int r = 0; r < 4; ++r) {
            const int t = t0 + c * 16 + hi * 4 + r;
            z[c][r] = (t <= srow) ? z[c][r] : -1e30f;
          }
      }
      float mt = z[0][0];
      #pragma unroll
      for (int c = 0; c < 4; ++c)
        #pragma unroll
        for (int r = 0; r < 4; ++r) mt = fmaxf(mt, z[c][r]);
      #pragma unroll
      for (int dd = 1; dd < 64; dd <<= 1) mt = fmaxf(mt, __shfl_xor(mt, dd));
      if (mt > hatm + 8.f) {  // defer-rescale (T13); mt wave-uniform -> uniform branch
        const float f = exp2f(hatm - mt);
        hatm = mt;
        l *= f;
        #pragma unroll
        for (int eb = 0; eb < 4; ++eb)
          #pragma unroll
          for (int r = 0; r < 4; ++r) acco[eb][r] *= f;
      }
      float ps[4][4];
      float sum = 0.f;
      #pragma unroll
      for (int c = 0; c < 4; ++c)
        #pragma unroll
        for (int r = 0; r < 4; ++r) {
          ps[c][r] = exp2f(z[c][r] - hatm);
          sum += ps[c][r];
        }
      l += sum;
      #pragma unroll
      for (int c = 0; c < 4; ++c) {
        uint2 pk;
        pk.x = (uint32_t)f2bf(ps[c][0]) | ((uint32_t)f2bf(ps[c][1]) << 16);
        pk.y = (uint32_t)f2bf(ps[c][2]) | ((uint32_t)f2bf(ps[c][3]) << 16);
        *reinterpret_cast<uint2*>(&pbuf[lo * 80 + c * 16 + hi * 4]) = pk;
      }
      asm volatile("s_waitcnt lgkmcnt(0)" ::: "memory");
      __builtin_amdgcn_sched_barrier(0);
      bf16x8 pa0 = *reinterpret_cast<const bf16x8*>(&pbuf[lo * 80 + hi * 8]);
      bf16x8 pa1 = *reinterpret_cast<const bf16x8*>(&pbuf[lo * 80 + 32 + hi * 8]);
      #pragma unroll
      for (int eb = 0; eb < 4; ++eb)
        acco[eb] = mfma16(pa1, vb[2 * eb + 1], mfma16(pa0, vb[2 * eb], acco[eb]));
    };

    PREF(kbA, vbA, 0);
    #pragma unroll 1
    for (int t0 = 0; t0 < send; t0 += 128) {
      STEP(kbA, vbA, kbB, vbB, t0);
      STEP(kbB, vbB, kbA, vbA, t0 + 64);
    }

    // row totals: l currently per-lane partial (its hi t-subset), common scale 2^-hatm
    l += __shfl_xor(l, 16);
    l += __shfl_xor(l, 32);
    const float offv = hatm + __log2f(l);
    if (lane < 16) off[bh + s0 + lo] = offv;
    float rinv[4];
    #pragma unroll
    for (int r = 0; r < 4; ++r) rinv[r] = 1.f / __shfl(l, hi * 4 + r);
    #pragma unroll
    for (int eb = 0; eb < 4; ++eb)
      #pragma unroll
      for (int r = 0; r < 4; ++r)
        outh[(bh + s0 + hi * 4 + r) * DHc + eb * 16 + lo] = f2bf(acco[eb][r] * rinv[r]);
  }
}

// ---------------- attn writer: one 128x128 tile per block, z^T layout, float4 stores.
// attn_out[b,s,h,t] = (t<=s) ? exp2(qh[s]·kh[t] - off[s]) : 0
__global__ __launch_bounds__(256) void attn_write(
    const u16* __restrict__ qh, const u16* __restrict__ kh,
    const float* __restrict__ off, float* __restrict__ attn_out) {
  const int tt = blockIdx.x, st = blockIdx.y, bhz = blockIdx.z;
  const int b = bhz >> 4, h = bhz & 15;
  const int s0 = st * 128, t0 = tt * 128;
  const int tid = threadIdx.x;
  const long rowstride = (long)Hc * Sc;
  float* aout = attn_out + (long)b * Sc * rowstride + (long)h * Sc;

  if (tt > st) {  // fully masked tile: coalesced zero fill
    const int r0 = tid >> 5, c0 = (tid & 31) * 4;
    const float4 z4 = {0.f, 0.f, 0.f, 0.f};
    #pragma unroll
    for (int pp = 0; pp < 16; ++pp)
      *reinterpret_cast<float4*>(&aout[(long)(s0 + pp * 8 + r0) * rowstride + t0 + c0]) = z4;
    return;
  }

  constexpr int LDP = 72;  // 64 + 8 pad
  __shared__ u16 Qs[128 * LDP];
  __shared__ u16 Ks[128 * LDP];
  const long bhS = (long)bhz * Sc;
  {
    const u16* qp = qh + (bhS + s0) * DHc;
    const u16* kp = kh + (bhS + t0) * DHc;
    #pragma unroll
    for (int it = 0; it < 4; ++it) {
      const int e = (tid + it * 256) * 8;  // 0..8191
      const int r = e >> 6, c = e & 63;
      *reinterpret_cast<uint4*>(&Qs[r * LDP + c]) =
          *reinterpret_cast<const uint4*>(&qp[r * 64 + c]);
      *reinterpret_cast<uint4*>(&Ks[r * LDP + c]) =
          *reinterpret_cast<const uint4*>(&kp[r * 64 + c]);
    }
  }
  __syncthreads();

  const int lane = tid & 63, w = tid >> 6;
  const int lo = lane & 15, hi = lane >> 4;
  const f32x4 vzero = {0.f, 0.f, 0.f, 0.f};
  const bool diag = (tt == st);

  bf16x8 qf[2][2];
  float offv[2];
  #pragma unroll
  for (int si = 0; si < 2; ++si) {
    const int srel = w * 32 + si * 16 + lo;
    qf[si][0] = *reinterpret_cast<const bf16x8*>(&Qs[srel * LDP + hi * 8]);
    qf[si][1] = *reinterpret_cast<const bf16x8*>(&Qs[srel * LDP + 32 + hi * 8]);
    offv[si] = off[bhS + s0 + srel];
  }

  #pragma unroll
  for (int tj = 0; tj < 8; ++tj) {
    bf16x8 a0 = *reinterpret_cast<const bf16x8*>(&Ks[(tj * 16 + lo) * LDP + hi * 8]);
    bf16x8 a1 = *reinterpret_cast<const bf16x8*>(&Ks[(tj * 16 + lo) * LDP + 32 + hi * 8]);
    #pragma unroll
    for (int si = 0; si < 2; ++si) {
      f32x4 z = mfma16(a1, qf[si][1], mfma16(a0, qf[si][0], vzero));
      const int srel = w * 32 + si * 16 + lo;
      float p[4];
      #pragma unroll
      for (int r = 0; r < 4; ++r) p[r] = exp2f(z[r] - offv[si]);
      if (diag && (tj * 16 + 15 > w * 32 + si * 16)) {
        #pragma unroll
        for (int r = 0; r < 4; ++r)
          p[r] = (tj * 16 + hi * 4 + r <= srel) ? p[r] : 0.f;
      }
      float4 v4 = {p[0], p[1], p[2], p[3]};
      *reinterpret_cast<float4*>(
          &aout[(long)(s0 + srel) * rowstride + t0 + tj * 16 + hi * 4]) = v4;
    }
  }
}

// ---------------- mean over heads
__global__ __launch_bounds__(256) void mean_kernel(const u16* __restrict__ outh,
                                                   u16* __restrict__ meanb) {
  const int idx = blockIdx.x * 256 + threadIdx.x;  // 32768 threads
  const int bs = idx >> 3;
  const int e0 = (idx & 7) * 8;
  const int b = bs >> 11, s = bs & 2047;
  float acc[8];
  #pragma unroll
  for (int j = 0; j < 8; ++j) acc[j] = 0.f;
  for (int h = 0; h < Hc; ++h) {
    alignas(16) u16 tmp[8];
    *reinterpret_cast<uint4*>(tmp) =
        *reinterpret_cast<const uint4*>(&outh[((long)(b * Hc + h) * Sc + s) * DHc + e0]);
    #pragma unroll
    for (int j = 0; j < 8; ++j) acc[j] += bf2f(tmp[j]);
  }
  alignas(16) u16 o[8];
  #pragma unroll
  for (int j = 0; j < 8; ++j) o[j] = f2bf(acc[j] * 0.0625f);
  *reinterpret_cast<uint4*>(&meanb[(long)bs * DHc + e0]) = *reinterpret_cast<const uint4*>(o);
}

extern "C" void kernel_launch(void* const* d_in, const int* in_sizes, int n_in,
                              void* d_out, int out_size, void* d_ws, size_t ws_size,
                              hipStream_t stream) {
  (void)in_sizes; (void)n_in; (void)out_size; (void)ws_size;
  const float* q  = (const float*)d_in[0];
  const float* k  = (const float*)d_in[1];
  const float* v  = (const float*)d_in[2];
  const float* Wv = (const float*)d_in[4];
  const float* bv = (const float*)d_in[5];
  const float* Wq = (const float*)d_in[6];
  const float* bq = (const float*)d_in[7];
  const float* Wk = (const float*)d_in[8];
  const float* bk = (const float*)d_in[9];
  const float* Wo = (const float*)d_in[10];

  char* ws = (char*)d_ws;
  u16*   qhb   = (u16*)(ws + 0);          // 8 MB  [B,H,S,DH]
  u16*   khb   = (u16*)(ws + 8388608);    // 8 MB
  u16*   vTb   = (u16*)(ws + 16777216);   // 512 KB [B,DH,S]
  u16*   outh  = (u16*)(ws + 17301504);   // 8 MB  [B,H,S,DH]
  u16*   meanb = (u16*)(ws + 25690112);   // 512 KB
  float* off   = (float*)(ws + 26214400); // 256 KB [B*H*S]

  float* outp  = (float*)d_out;
  float* attnp = (float*)d_out + (long)Bc * Sc * Dc;

  const int M = Bc * Sc;  // 4096
  // qh scale folds 1/sqrt(DH) AND log2(e) (attn runs in exp2 domain)
  const float qscale = 0.125f * 1.4426950408889634f;
  gemm_bt<true><<<dim3(8, 32), 256, 0, stream>>>(q, Wq, bq, M, 1024, 1024, qscale,
      qhb, nullptr, 64, 2097152L, 64L, 131072L, 1L);
  gemm_bt<true><<<dim3(8, 32), 256, 0, stream>>>(k, Wk, bk, M, 1024, 1024, 1.0f,
      khb, nullptr, 64, 2097152L, 64L, 131072L, 1L);
  gemm_bt<true><<<dim3(1, 32), 256, 0, stream>>>(v, Wv, bv, M, 64, 1024, 1.0f,
      vTb, nullptr, 64, 131072L, 1L, 0L, 2048L);

  attn_stats<<<512, 256, 0, stream>>>(qhb, khb, vTb, outh, off);

  attn_write<<<dim3(16, 16, Bc * Hc), 256, 0, stream>>>(qhb, khb, off, attnp);

  mean_kernel<<<128, 256, 0, stream>>>(outh, meanb);

  gemm_bt<false><<<dim3(8, 32), 256, 0, stream>>>(meanb, Wo, nullptr, M, 1024, 64, 1.0f,
      nullptr, outp, 1024, 2097152L, 1024L, 0L, 1L);
}